// Round 2
// baseline (1474.414 us; speedup 1.0000x reference)
//
#include <hip/hip_runtime.h>

#define NU 10000
#define NI 12000
#define RK 64
#define LDSS 68      // LDS row stride in floats: 16B-aligned rows, bank-rotation 4
#define KSPLIT 8

#define FMA16(A, B, ACC)                                                     \
    ACC[0][0] = fmaf(A.x, B.x, ACC[0][0]); ACC[0][1] = fmaf(A.x, B.y, ACC[0][1]); \
    ACC[0][2] = fmaf(A.x, B.z, ACC[0][2]); ACC[0][3] = fmaf(A.x, B.w, ACC[0][3]); \
    ACC[1][0] = fmaf(A.y, B.x, ACC[1][0]); ACC[1][1] = fmaf(A.y, B.y, ACC[1][1]); \
    ACC[1][2] = fmaf(A.y, B.z, ACC[1][2]); ACC[1][3] = fmaf(A.y, B.w, ACC[1][3]); \
    ACC[2][0] = fmaf(A.z, B.x, ACC[2][0]); ACC[2][1] = fmaf(A.z, B.y, ACC[2][1]); \
    ACC[2][2] = fmaf(A.z, B.z, ACC[2][2]); ACC[2][3] = fmaf(A.z, B.w, ACC[2][3]); \
    ACC[3][0] = fmaf(A.w, B.x, ACC[3][0]); ACC[3][1] = fmaf(A.w, B.y, ACC[3][1]); \
    ACC[3][2] = fmaf(A.w, B.z, ACC[3][2]); ACC[3][3] = fmaf(A.w, B.w, ACC[3][3]);

__device__ __forceinline__ void load16f(const float* p, float* v) {
#pragma unroll
    for (int j = 0; j < 4; ++j) {
        float4 f = ((const float4*)p)[j];
        v[4 * j] = f.x; v[4 * j + 1] = f.y; v[4 * j + 2] = f.z; v[4 * j + 3] = f.w;
    }
}

// leftS[u][r] = (1/lam[r]) * sum_i nadj[u][i] * isv[i][r]   (atomic-accumulated)
__global__ __launch_bounds__(256) void kernelA(const float* __restrict__ nadj,
                                               const float* __restrict__ isv,
                                               const float* __restrict__ lam,
                                               float* __restrict__ leftS) {
    __shared__ float aT[64 * LDSS];  // [kk][u]  (transposed nadj tile)
    __shared__ float bS[64 * LDSS];  // [kk][r]
    const int t    = threadIdx.x;
    const int u0   = blockIdx.x * 64;
    const int row  = t >> 2;
    const int colb = (t & 3) * 16;
    const int tr   = t & 15;
    const int tu   = t >> 4;

    float invl[4];
#pragma unroll
    for (int c = 0; c < 4; ++c) invl[c] = 1.0f / lam[tr * 4 + c];

    float acc[4][4] = {{0.f, 0.f, 0.f, 0.f}};

    const int nch = (NI + 63) / 64;  // 188
    for (int ch = blockIdx.y; ch < nch; ch += KSPLIT) {
        const int k0 = ch * 64;
        {   // nadj tile -> aT[kk][u], transpose in LDS
            float v[16];
            const int gu = u0 + row;
            const int gk = k0 + colb;
            if (gu < NU && gk + 15 < NI) {
                load16f(nadj + (size_t)gu * NI + gk, v);
            } else {
#pragma unroll
                for (int j = 0; j < 16; ++j) v[j] = 0.f;
            }
#pragma unroll
            for (int j = 0; j < 16; ++j) aT[(colb + j) * LDSS + row] = v[j];
        }
        {   // isv chunk -> bS[kk][r], row-major
            float v[16];
            const int gk = k0 + row;
            if (gk < NI) {
                load16f(isv + (size_t)gk * RK + colb, v);
            } else {
#pragma unroll
                for (int j = 0; j < 16; ++j) v[j] = 0.f;
            }
#pragma unroll
            for (int j = 0; j < 4; ++j)
                *(float4*)&bS[row * LDSS + colb + 4 * j] =
                    make_float4(v[4 * j], v[4 * j + 1], v[4 * j + 2], v[4 * j + 3]);
        }
        __syncthreads();
#pragma unroll 4
        for (int kk = 0; kk < 64; ++kk) {
            const float4 a = *(const float4*)&aT[kk * LDSS + tu * 4];
            const float4 b = *(const float4*)&bS[kk * LDSS + tr * 4];
            FMA16(a, b, acc)
        }
        __syncthreads();
    }
#pragma unroll
    for (int cu = 0; cu < 4; ++cu) {
        const int gu = u0 + tu * 4 + cu;
        if (gu < NU) {
#pragma unroll
            for (int cr = 0; cr < 4; ++cr)
                atomicAdd(&leftS[(size_t)gu * RK + tr * 4 + cr], acc[cu][cr] * invl[cr]);
        }
    }
}

// rightT[i][r] = sum_u adj[u][i] * usv[u][r]   (atomic-accumulated)
__global__ __launch_bounds__(256) void kernelB(const float* __restrict__ adj,
                                               const float* __restrict__ usv,
                                               float* __restrict__ rightT) {
    __shared__ float aS[64 * LDSS];  // [kk][i]
    __shared__ float bS[64 * LDSS];  // [kk][r]
    const int t    = threadIdx.x;
    const int i0   = blockIdx.x * 64;
    const int row  = t >> 2;
    const int colb = (t & 3) * 16;
    const int tr   = t & 15;
    const int ti   = t >> 4;

    float acc[4][4] = {{0.f, 0.f, 0.f, 0.f}};

    const int nch = (NU + 63) / 64;  // 157
    for (int ch = blockIdx.y; ch < nch; ch += KSPLIT) {
        const int k0 = ch * 64;
        {   // adj tile -> aS[kk][i], row-major (no transpose needed)
            float v[16];
            const int gu = k0 + row;
            const int gi = i0 + colb;
            if (gu < NU && gi + 15 < NI) {
                load16f(adj + (size_t)gu * NI + gi, v);
            } else {
#pragma unroll
                for (int j = 0; j < 16; ++j) v[j] = 0.f;
            }
#pragma unroll
            for (int j = 0; j < 4; ++j)
                *(float4*)&aS[row * LDSS + colb + 4 * j] =
                    make_float4(v[4 * j], v[4 * j + 1], v[4 * j + 2], v[4 * j + 3]);
        }
        {   // usv chunk -> bS[kk][r], row-major
            float v[16];
            const int gu = k0 + row;
            if (gu < NU) {
                load16f(usv + (size_t)gu * RK + colb, v);
            } else {
#pragma unroll
                for (int j = 0; j < 16; ++j) v[j] = 0.f;
            }
#pragma unroll
            for (int j = 0; j < 4; ++j)
                *(float4*)&bS[row * LDSS + colb + 4 * j] =
                    make_float4(v[4 * j], v[4 * j + 1], v[4 * j + 2], v[4 * j + 3]);
        }
        __syncthreads();
#pragma unroll 4
        for (int kk = 0; kk < 64; ++kk) {
            const float4 a = *(const float4*)&aS[kk * LDSS + ti * 4];
            const float4 b = *(const float4*)&bS[kk * LDSS + tr * 4];
            FMA16(a, b, acc)
        }
        __syncthreads();
    }
#pragma unroll
    for (int ci = 0; ci < 4; ++ci) {
        const int gi = i0 + ti * 4 + ci;
        if (gi < NI) {
#pragma unroll
            for (int cr = 0; cr < 4; ++cr)
                atomicAdd(&rightT[(size_t)gi * RK + tr * 4 + cr], acc[ci][cr]);
        }
    }
}

// rating[u][i] = sum_r leftS[u][r] * rightT[i][r]   (leftS already scaled by 1/lam)
__global__ __launch_bounds__(256) void kernelC(const float* __restrict__ leftS,
                                               const float* __restrict__ rightT,
                                               float* __restrict__ out) {
    __shared__ float lT[64 * LDSS];  // [r][u]
    __shared__ float rT[64 * LDSS];  // [r][i]
    const int t    = threadIdx.x;
    const int u0   = blockIdx.x * 64;
    const int i0   = blockIdx.y * 64;
    const int row  = t >> 2;
    const int colb = (t & 3) * 16;

    {   // leftS tile -> lT[r][u] (transpose)
        float v[16];
        const int gu = u0 + row;
        if (gu < NU) {
            load16f(leftS + (size_t)gu * RK + colb, v);
        } else {
#pragma unroll
            for (int j = 0; j < 16; ++j) v[j] = 0.f;
        }
#pragma unroll
        for (int j = 0; j < 16; ++j) lT[(colb + j) * LDSS + row] = v[j];
    }
    {   // rightT tile -> rT[r][i] (transpose)
        float v[16];
        const int gi = i0 + row;
        if (gi < NI) {
            load16f(rightT + (size_t)gi * RK + colb, v);
        } else {
#pragma unroll
            for (int j = 0; j < 16; ++j) v[j] = 0.f;
        }
#pragma unroll
        for (int j = 0; j < 16; ++j) rT[(colb + j) * LDSS + row] = v[j];
    }
    __syncthreads();

    const int ti = t & 15;
    const int tu = t >> 4;
    float acc[4][4] = {{0.f, 0.f, 0.f, 0.f}};  // [cu][ci]
#pragma unroll 4
    for (int r = 0; r < 64; ++r) {
        const float4 a = *(const float4*)&lT[r * LDSS + tu * 4];  // u
        const float4 b = *(const float4*)&rT[r * LDSS + ti * 4];  // i
        FMA16(a, b, acc)
    }
#pragma unroll
    for (int cu = 0; cu < 4; ++cu) {
        const int gu = u0 + tu * 4 + cu;
        const int gi = i0 + ti * 4;
        if (gu < NU && gi + 3 < NI) {
            *(float4*)(out + (size_t)gu * NI + gi) =
                make_float4(acc[cu][0], acc[cu][1], acc[cu][2], acc[cu][3]);
        }
    }
}

extern "C" void kernel_launch(void* const* d_in, const int* in_sizes, int n_in,
                              void* d_out, int out_size, void* d_ws, size_t ws_size,
                              hipStream_t stream) {
    const float* lam  = (const float*)d_in[0];  // lambda_mat [64]
    const float* usv  = (const float*)d_in[1];  // user_sv [U,64]
    const float* isv  = (const float*)d_in[2];  // item_sv [I,64]
    const float* adj  = (const float*)d_in[3];  // adj_mat [U,I]
    const float* nadj = (const float*)d_in[4];  // norm_adj [U,I]
    float* out = (float*)d_out;

    float* leftS  = (float*)d_ws;                  // [U,64] f32, pre-scaled by 1/lam
    float* rightT = leftS + (size_t)NU * RK;       // [I,64] f32

    hipMemsetAsync(d_ws, 0, ((size_t)NU * RK + (size_t)NI * RK) * sizeof(float), stream);

    kernelA<<<dim3((NU + 63) / 64, KSPLIT), 256, 0, stream>>>(nadj, isv, lam, leftS);
    kernelB<<<dim3((NI + 63) / 64, KSPLIT), 256, 0, stream>>>(adj, usv, rightT);
    kernelC<<<dim3((NU + 63) / 64, (NI + 63) / 64), 256, 0, stream>>>(leftS, rightT, out);
}